// Round 7
// baseline (1268.763 us; speedup 1.0000x reference)
//
#include <hip/hip_runtime.h>
#include <math.h>

#define GRID 256
#define BLK 512
#define NTHR 131072   // GRID*BLK

typedef __attribute__((ext_vector_type(8))) _Float16 half8;
typedef __attribute__((ext_vector_type(4))) float floatx4;

struct P {
    const float* x; const int* ei; const float* eattr; const int* batch;
    const float *lin0_w, *lin0_b, *nn_w1, *nn_b1, *nn_w2, *nn_b2;
    const float *root_w, *conv_b, *gwih, *gwhh, *gbih, *gbhh;
    const float *l1w, *l1b, *l2w, *l2b;
    float* out;
    float *agg0, *pooled, *cnt, *deg, *xh, *g1, *g2, *ehP;
    _Float16 *bigC, *Ax, *BTu, *Bih, *Bhh;
    unsigned* bar;
};

__device__ __forceinline__ void ldst16(const _Float16* g, void* l) {
    __builtin_amdgcn_global_load_lds(
        (const __attribute__((address_space(1))) unsigned int*)g,
        (__attribute__((address_space(3))) unsigned int*)l, 16, 0, 0);
}

// device-scope grid barrier: monotone counter, target = 256*k.
// __threadfence (agent-scope fence) provides the L2 wb / L1+L2 inv needed for
// cross-XCD visibility (G16); 1 block/CU so thread0's inv covers its CU.
__device__ __forceinline__ void gridbar(unsigned* cnt, unsigned target) {
    __syncthreads();
    if (threadIdx.x == 0) {
        __threadfence();
        __hip_atomic_fetch_add(cnt, 1u, __ATOMIC_RELEASE, __HIP_MEMORY_SCOPE_AGENT);
        while (__hip_atomic_load(cnt, __ATOMIC_ACQUIRE, __HIP_MEMORY_SCOPE_AGENT) < target)
            __builtin_amdgcn_s_sleep(2);
        __threadfence();
    }
    __syncthreads();
}

// ---------------------------------------------------------------------------
// 128x128 fp16 MFMA tile (R4-verified body), quad-local (tq in [0,256)).
// Barriers are block-wide and unconditional; work is guarded by `active`.
// ---------------------------------------------------------------------------
__device__ __forceinline__ void mgemm_quad(
    int active, int tq, const _Float16* __restrict__ A,
    const _Float16* __restrict__ B, _Float16* __restrict__ C,
    int tx, int ty, _Float16* As, _Float16* Bs)
{
    const int lane = tq & 63, wave = tq >> 6;
    const int m0 = ty * 128, n0 = tx * 128;
    const int wr = (wave >> 1) * 64, wc = (wave & 1) * 64;
    const int fm = lane & 15, fq = lane >> 4;

    const int srow = tq >> 2, soff = (tq & 3) << 3;
    const _Float16* gA0 = A + (size_t)(m0 + srow) * 128 + soff;
    const _Float16* gA1 = gA0 + (size_t)64 * 128;
    const _Float16* gB0 = B + (size_t)(n0 + srow) * 128 + soff;
    const _Float16* gB1 = gB0 + (size_t)64 * 128;
    char* lA0 = (char*)As + tq * 16;  char* lA1 = (char*)As + (tq + 256) * 16;
    char* lB0 = (char*)Bs + tq * 16;  char* lB1 = (char*)Bs + (tq + 256) * 16;

    floatx4 acc[4][4] = {};
    for (int k0 = 0; k0 < 128; k0 += 32) {
        __syncthreads();
        if (active) {
            ldst16(gA0 + k0, lA0); ldst16(gA1 + k0, lA1);
            ldst16(gB0 + k0, lB0); ldst16(gB1 + k0, lB1);
        }
        __syncthreads();
        if (active) {
            half8 af[4], bf[4];
#pragma unroll
            for (int i = 0; i < 4; ++i)
                af[i] = *(const half8*)&As[(wr + i * 16 + fm) * 32 + fq * 8];
#pragma unroll
            for (int j = 0; j < 4; ++j)
                bf[j] = *(const half8*)&Bs[(wc + j * 16 + fm) * 32 + fq * 8];
#pragma unroll
            for (int i = 0; i < 4; ++i)
#pragma unroll
                for (int j = 0; j < 4; ++j)
                    acc[i][j] = __builtin_amdgcn_mfma_f32_16x16x32_f16(
                        af[i], bf[j], acc[i][j], 0, 0, 0);
        }
    }
    if (active) {
        // C/D layout: col = lane&15, row = (lane>>4)*4 + reg  [m89]
        const int er = fq * 4, ec = fm;
#pragma unroll
        for (int i = 0; i < 4; ++i) {
            const int gr = m0 + wr + i * 16 + er;
#pragma unroll
            for (int j = 0; j < 4; ++j) {
                const int gc = n0 + wc + j * 16 + ec;
#pragma unroll
                for (int r = 0; r < 4; ++r)
                    C[(size_t)(gr + r) * 4352 + gc] = (_Float16)acc[i][j][r];
            }
        }
    }
}

// ---------------------------------------------------------------------------
// GRU gate GEMM tile (z=0: gi = m@wih^T+bih, mcomb+inv-deg fused into staging;
// z=1: gh = h@whh^T+bhh). Quad-local, LDS rows padded to 40 halves.
// ---------------------------------------------------------------------------
__device__ __forceinline__ void gru_quad(
    int active, int tq, const P& p, int z, int gx, int gy,
    const float* agg, const float* cb, _Float16* As, _Float16* Bs)
{
    const _Float16* B = z ? p.Bhh : p.Bih;
    const float* bias = z ? p.gbhh : p.gbih;
    float* C = z ? p.g2 : p.g1;
    const int lane = tq & 63, wave = tq >> 6;
    const int m0 = gy * 128, n0 = gx * 128;
    const int wr = (wave >> 1) * 64, wc = (wave & 1) * 64;
    const int fm = lane & 15, fq = lane >> 4;

    floatx4 acc[4][4] = {};
    for (int k0 = 0; k0 < 128; k0 += 32) {
        __syncthreads();
        if (active) {
#pragma unroll
            for (int c = tq; c < 512; c += 256) {
                const int row = c >> 2, seg = (c & 3) << 3;
                if (z == 0) {
                    const int mr = m0 + row;
                    const float d = p.deg[mr];
                    const float inv = d > 0.f ? 1.0f / d : 0.0f;
                    const half8 bv = *(const half8*)&p.bigC[(size_t)mr * 4352 + 4224 + k0 + seg];
                    const float4 a0 = *(const float4*)&agg[(size_t)mr * 128 + k0 + seg];
                    const float4 a1 = *(const float4*)&agg[(size_t)mr * 128 + k0 + seg + 4];
                    const float4 c0 = *(const float4*)&cb[k0 + seg];
                    const float4 c1 = *(const float4*)&cb[k0 + seg + 4];
                    _Float16 v8[8];
                    v8[0] = (_Float16)fmaxf((float)bv[0] + a0.x * inv + c0.x, 0.f);
                    v8[1] = (_Float16)fmaxf((float)bv[1] + a0.y * inv + c0.y, 0.f);
                    v8[2] = (_Float16)fmaxf((float)bv[2] + a0.z * inv + c0.z, 0.f);
                    v8[3] = (_Float16)fmaxf((float)bv[3] + a0.w * inv + c0.w, 0.f);
                    v8[4] = (_Float16)fmaxf((float)bv[4] + a1.x * inv + c1.x, 0.f);
                    v8[5] = (_Float16)fmaxf((float)bv[5] + a1.y * inv + c1.y, 0.f);
                    v8[6] = (_Float16)fmaxf((float)bv[6] + a1.z * inv + c1.z, 0.f);
                    v8[7] = (_Float16)fmaxf((float)bv[7] + a1.w * inv + c1.w, 0.f);
                    *(half8*)&As[row * 40 + seg] = *(half8*)v8;
                } else {
                    *(half8*)&As[row * 40 + seg] =
                        *(const half8*)&p.Ax[(size_t)(m0 + row) * 128 + k0 + seg];
                }
                *(half8*)&Bs[row * 40 + seg] =
                    *(const half8*)&B[(size_t)(n0 + row) * 128 + k0 + seg];
            }
        }
        __syncthreads();
        if (active) {
            half8 af[4], bf[4];
#pragma unroll
            for (int i = 0; i < 4; ++i)
                af[i] = *(const half8*)&As[(wr + i * 16 + fm) * 40 + fq * 8];
#pragma unroll
            for (int j = 0; j < 4; ++j)
                bf[j] = *(const half8*)&Bs[(wc + j * 16 + fm) * 40 + fq * 8];
#pragma unroll
            for (int i = 0; i < 4; ++i)
#pragma unroll
                for (int j = 0; j < 4; ++j)
                    acc[i][j] = __builtin_amdgcn_mfma_f32_16x16x32_f16(
                        af[i], bf[j], acc[i][j], 0, 0, 0);
        }
    }
    if (active) {
        const int er = fq * 4, ec = fm;
#pragma unroll
        for (int i = 0; i < 4; ++i) {
            const int gr = m0 + wr + i * 16 + er;
#pragma unroll
            for (int j = 0; j < 4; ++j) {
                const int gc = n0 + wc + j * 16 + ec;
                const float bv = bias[gc];
#pragma unroll
                for (int r = 0; r < 4; ++r)
                    C[(size_t)(gr + r) * 384 + gc] = acc[i][j][r] + bv;
            }
        }
    }
}

// lin0 64x64 fp32 tile: xh = relu(x[4096,64]@w[64,128]+b); also Ax fp16
__device__ __forceinline__ void lin0_quad(int active, int tq, const P& p,
                                          int jx, int my, float* As, float* Bs)
{
    const int tx = tq & 15, ty = tq >> 4;
    const int j0 = jx * 64, m0 = my * 64;
    const int arow = tq >> 2, acol = (tq & 3) << 2;
    const int bk = tq >> 4, bj = (tq & 15) << 2;

    float c[4][4] = {};
    for (int k0 = 0; k0 < 64; k0 += 16) {
        __syncthreads();
        if (active) {
            float4 av = *(const float4*)&p.x[(size_t)(m0 + arow) * 64 + k0 + acol];
            As[(acol + 0) * 64 + arow] = av.x;
            As[(acol + 1) * 64 + arow] = av.y;
            As[(acol + 2) * 64 + arow] = av.z;
            As[(acol + 3) * 64 + arow] = av.w;
            *(float4*)&Bs[bk * 64 + bj] =
                *(const float4*)&p.lin0_w[(size_t)(k0 + bk) * 128 + j0 + bj];
        }
        __syncthreads();
        if (active) {
#pragma unroll
            for (int kk = 0; kk < 16; ++kk) {
                const float4 a = *(const float4*)&As[kk * 64 + (ty << 2)];
                const float4 b = *(const float4*)&Bs[kk * 64 + (tx << 2)];
                c[0][0] += a.x * b.x; c[0][1] += a.x * b.y; c[0][2] += a.x * b.z; c[0][3] += a.x * b.w;
                c[1][0] += a.y * b.x; c[1][1] += a.y * b.y; c[1][2] += a.y * b.z; c[1][3] += a.y * b.w;
                c[2][0] += a.z * b.x; c[2][1] += a.z * b.y; c[2][2] += a.z * b.z; c[2][3] += a.z * b.w;
                c[3][0] += a.w * b.x; c[3][1] += a.w * b.y; c[3][2] += a.w * b.z; c[3][3] += a.w * b.w;
            }
        }
    }
    if (active) {
        const float4 bv = *(const float4*)&p.lin0_b[j0 + (tx << 2)];
        const int col0 = j0 + (tx << 2);
#pragma unroll
        for (int i = 0; i < 4; ++i) {
            const int row = m0 + (ty << 2) + i;
            float4 o;
            o.x = fmaxf(c[i][0] + bv.x, 0.f); o.y = fmaxf(c[i][1] + bv.y, 0.f);
            o.z = fmaxf(c[i][2] + bv.z, 0.f); o.w = fmaxf(c[i][3] + bv.w, 0.f);
            *(float4*)&p.xh[(size_t)row * 128 + col0] = o;
            _Float16* base = p.Ax + (size_t)row * 128 + col0;
            base[0] = (_Float16)o.x; base[1] = (_Float16)o.y;
            base[2] = (_Float16)o.z; base[3] = (_Float16)o.w;
        }
    }
}

// ---------------------------------------------------------------------------
// Persistent mega-kernel: normal launch, 256 blocks x 512 threads (1 block/CU
// guaranteed co-resident), software grid barrier, 13 sync points.
// Each block = 2 quads of 256 threads running the R4-verified tile bodies.
// ---------------------------------------------------------------------------
__global__ __launch_bounds__(512, 2) void mega_k(P p)
{
    __shared__ __align__(16) char smem[41984];
    const int bid = blockIdx.x;
    const int tid = threadIdx.x;
    const int gtid = bid * 512 + tid;
    const int quad = tid >> 8, tq = tid & 255;
    char* qb = smem + quad * 20992;
    unsigned bt = 0;

    // ---------------- INIT ----------------
    {   // zero region: agg0(3x524288) | pooled(1024) | cnt(8) | deg(4096)
        float4 z = {0.f, 0.f, 0.f, 0.f};
        for (int i = gtid; i < 394498; i += NTHR) ((float4*)p.agg0)[i] = z;
    }
    for (int i = gtid; i < 49152; i += NTHR) {     // [384,128] each
        p.Bih[i] = (_Float16)p.gwih[i];
        p.Bhh[i] = (_Float16)p.gwhh[i];
    }
    for (int i = gtid; i < 1671168; i += NTHR) {   // BTu[t][j][h]
        const int t = i / 557056, rem = i - t * 557056;
        const int j = rem >> 7, h = rem & 127;
        float v;
        if (j < 4096)      v = p.nn_w2[t * 524288 + (j >> 7) * 16384 + h * 128 + (j & 127)];
        else if (j < 4224) v = p.nn_b2[t * 16384 + h * 128 + (j - 4096)];
        else               v = p.root_w[t * 16384 + h * 128 + (j - 4224)];
        p.BTu[i] = (_Float16)v;
    }
    for (int u = gtid; u < 24576; u += NTHR) {     // ehP[t][e][33], no inv
        const int t = u >> 13, e = u & 8191;
        const float ea = p.eattr[e];
        float* dst = p.ehP + (size_t)u * 33;
        for (int k = 0; k < 32; ++k) {
            float v = ea * p.nn_w1[t * 32 + k] + p.nn_b1[t * 32 + k];
            dst[k] = v > 0.f ? v : 0.f;
        }
        dst[32] = 1.0f;
    }
    {   // lin0: 128 tiles over 512 quad-slots
        const int slot = bid * 2 + quad;
        lin0_quad(slot < 128, tq, p, slot & 1, slot >> 1,
                  (float*)qb, (float*)(qb + 4096));
    }
    bt += GRID; gridbar(p.bar, bt);

    for (int t = 0; t < 3; ++t) {
        // ---- A: big GEMM bigC = Ax @ [W2|b2|root]^T (+hists on t==0) ----
        if (t == 0) {
            if (gtid < 8192)        atomicAdd(&p.deg[p.ei[8192 + gtid]], 1.0f);
            else if (gtid < 12288)  atomicAdd(&p.cnt[p.batch[gtid - 8192]], 1.0f);
        }
        const _Float16* BT = p.BTu + (size_t)t * 557056;
        for (int i = 0; i < 3; ++i) {               // 1088 tiles over 3x512 slots
            const int v = i * 512 + bid * 2 + quad;
            mgemm_quad(v < 1088, tq, p.Ax, BT, p.bigC, v % 34, v / 34,
                       (_Float16*)qb, (_Float16*)(qb + 8192));
        }
        bt += GRID; gridbar(p.bar, bt);

        // ---- B: edge gather + scatter ----
        float* agg = p.agg0 + (size_t)t * 524288;
        const float* ehPt = p.ehP + (size_t)t * 8192 * 33;
        {
            const int grp = (bid * 512 + tid) >> 7;  // 1024 groups of 128 thr
            const int o = tid & 127;
            for (int e = grp; e < 8192; e += 1024) {
                const int r = p.ei[e], c = p.ei[8192 + e];
                const _Float16* Ur = p.bigC + (size_t)r * 4352;
                const float* eh = ehPt + (size_t)e * 33;
                float acc = (float)Ur[4096 + o];     // b2 slice, coeff 1
#pragma unroll
                for (int k = 0; k < 32; ++k) acc += eh[k] * (float)Ur[k * 128 + o];
                atomicAdd(&agg[(size_t)c * 128 + o], acc);
            }
        }
        bt += GRID; gridbar(p.bar, bt);

        // ---- C: GRU gate GEMMs (192 tiles over 512 slots) ----
        {
            const int slot = bid * 2 + quad;
            const int z = slot & 1, rest = slot >> 1;
            gru_quad(slot < 192, tq, p, z, rest % 3, rest / 3, agg,
                     p.conv_b + t * 128, (_Float16*)qb, (_Float16*)(qb + 10240));
        }
        bt += GRID; gridbar(p.bar, bt);

        // ---- D: gate combine (+pool on t==2) ----
        for (int idx = gtid; idx < 524288; idx += NTHR) {
            const int n = idx >> 7, o = idx & 127;
            const size_t b = (size_t)n * 384;
            float ir = p.g1[b + o], iz = p.g1[b + 128 + o], inn = p.g1[b + 256 + o];
            float hr = p.g2[b + o], hz = p.g2[b + 128 + o], hn = p.g2[b + 256 + o];
            float r = 1.f / (1.f + expf(-(ir + hr)));
            float zz = 1.f / (1.f + expf(-(iz + hz)));
            float nv = tanhf(inn + r * hn);
            float hv = (1.f - zz) * nv + zz * p.xh[idx];
            p.xh[idx] = hv;
            p.Ax[idx] = (_Float16)hv;
            if (t == 2) atomicAdd(&p.pooled[p.batch[n] * 128 + o], hv);
        }
        bt += GRID; gridbar(p.bar, bt);
    }

    // ---------------- FINAL (block 0) ----------------
    if (bid == 0) {
        float* gv = (float*)smem;
        float* sy = (float*)(smem + 512);
        for (int g = 0; g < 8; ++g) {
            if (tid < 128) {
                float c = p.cnt[g]; c = c > 1.f ? c : 1.f;
                gv[tid] = p.pooled[g * 128 + tid] / c;
            }
            __syncthreads();
            if (tid < 64) {
                float y = p.l1b[tid];
                for (int h = 0; h < 128; ++h) y += gv[h] * p.l1w[h * 64 + tid];
                y = y > 0.f ? y : 0.f;
                sy[tid] = y * p.l2w[tid];
            }
            __syncthreads();
            if (tid == 0) {
                float s = p.l2b[0];
                for (int j = 0; j < 64; ++j) s += sy[j];
                p.out[g] = s;
            }
            __syncthreads();
        }
    }
}

extern "C" void kernel_launch(void* const* d_in, const int* in_sizes, int n_in,
                              void* d_out, int out_size, void* d_ws, size_t ws_size,
                              hipStream_t stream) {
    float* ws = (float*)d_ws;
    P p;
    p.x      = (const float*)d_in[0];
    p.ei     = (const int*)d_in[1];
    p.eattr  = (const float*)d_in[2];
    p.batch  = (const int*)d_in[3];
    p.lin0_w = (const float*)d_in[4];
    p.lin0_b = (const float*)d_in[5];
    p.nn_w1  = (const float*)d_in[6];
    p.nn_b1  = (const float*)d_in[7];
    p.nn_w2  = (const float*)d_in[8];
    p.nn_b2  = (const float*)d_in[9];
    p.root_w = (const float*)d_in[10];
    p.conv_b = (const float*)d_in[11];
    p.gwih   = (const float*)d_in[12];
    p.gwhh   = (const float*)d_in[13];
    p.gbih   = (const float*)d_in[14];
    p.gbhh   = (const float*)d_in[15];
    p.l1w    = (const float*)d_in[16];
    p.l1b    = (const float*)d_in[17];
    p.l2w    = (const float*)d_in[18];
    p.l2b    = (const float*)d_in[19];
    p.out    = (float*)d_out;

    // workspace layout (float offsets); zero region [agg0..deg] contiguous
    p.agg0   = ws;                            // 3 x [4096,128]
    p.pooled = ws + 1572864;                  // [8,128]
    p.cnt    = ws + 1573888;                  // [8]
    p.deg    = ws + 1573896;                  // [4096]  (zero region ends 1577992)
    p.xh     = ws + 1577992;                  // [4096,128] fp32
    p.g1     = ws + 2102280;                  // [4096,384] fp32
    p.g2     = ws + 3675144;                  // [4096,384] fp32
    p.ehP    = ws + 5248008;                  // [3,8192,33] fp32
    p.bigC   = (_Float16*)(ws + 6059016);     // [4096,4352] fp16
    p.Ax     = (_Float16*)(ws + 14971912);    // [4096,128] fp16
    p.BTu    = (_Float16*)(ws + 15234056);    // 3 x [4352,128] fp16
    p.Bih    = (_Float16*)(ws + 16069640);    // [384,128] fp16
    p.Bhh    = (_Float16*)(ws + 16094216);    // [384,128] fp16
    p.bar    = (unsigned*)(ws + 16118792);    // barrier counter

    hipMemsetAsync(p.bar, 0, 64, stream);
    mega_k<<<dim3(GRID), dim3(BLK), 0, stream>>>(p);
}

// Round 8
// 324.991 us; speedup vs baseline: 3.9040x; 3.9040x over previous
//
#include <hip/hip_runtime.h>
#include <math.h>

#define NN 4096
#define EE 8192
#define HH 128
#define GG 8
#define ULD 4352          // big GEMM cols: 4096 (W2) + 128 (b2) + 128 (root)

typedef __attribute__((ext_vector_type(8))) _Float16 half8;
typedef __attribute__((ext_vector_type(4))) float floatx4;

__device__ __forceinline__ void ldst16(const _Float16* g, void* l) {
    __builtin_amdgcn_global_load_lds(
        (const __attribute__((address_space(1))) unsigned int*)g,
        (__attribute__((address_space(3))) unsigned int*)l, 16, 0, 0);
}

// ---------------------------------------------------------------------------
// fp16 MFMA GEMM (R4-verified): C[M,ULD] = A[M,128] @ BT[N,128]^T, C fp16.
// 128x128 tile/block, 4 waves (2x2 of 64x64), BK=32, K=128.
// ---------------------------------------------------------------------------
__global__ __launch_bounds__(256) void mgemm16_k(
    const _Float16* __restrict__ A, const _Float16* __restrict__ B,
    _Float16* __restrict__ C)
{
    __shared__ __align__(16) _Float16 As[128 * 32];  // [row][k]
    __shared__ __align__(16) _Float16 Bs[128 * 32];  // [col][k]
    const int tid = threadIdx.x;
    const int lane = tid & 63, wave = tid >> 6;
    const int m0 = blockIdx.y * 128, n0 = blockIdx.x * 128;
    const int wr = (wave >> 1) * 64, wc = (wave & 1) * 64;
    const int fm = lane & 15, fq = lane >> 4;

    const int srow = tid >> 2, soff = (tid & 3) << 3;
    const _Float16* gA0 = A + (size_t)(m0 + srow) * 128 + soff;
    const _Float16* gA1 = gA0 + (size_t)64 * 128;
    const _Float16* gB0 = B + (size_t)(n0 + srow) * 128 + soff;
    const _Float16* gB1 = gB0 + (size_t)64 * 128;
    char* lA0 = (char*)As + tid * 16;  char* lA1 = (char*)As + (tid + 256) * 16;
    char* lB0 = (char*)Bs + tid * 16;  char* lB1 = (char*)Bs + (tid + 256) * 16;

    floatx4 acc[4][4] = {};
    for (int k0 = 0; k0 < 128; k0 += 32) {
        __syncthreads();
        ldst16(gA0 + k0, lA0); ldst16(gA1 + k0, lA1);
        ldst16(gB0 + k0, lB0); ldst16(gB1 + k0, lB1);
        __syncthreads();
        half8 af[4], bf[4];
#pragma unroll
        for (int i = 0; i < 4; ++i)
            af[i] = *(const half8*)&As[(wr + i * 16 + fm) * 32 + fq * 8];
#pragma unroll
        for (int j = 0; j < 4; ++j)
            bf[j] = *(const half8*)&Bs[(wc + j * 16 + fm) * 32 + fq * 8];
#pragma unroll
        for (int i = 0; i < 4; ++i)
#pragma unroll
            for (int j = 0; j < 4; ++j)
                acc[i][j] = __builtin_amdgcn_mfma_f32_16x16x32_f16(
                    af[i], bf[j], acc[i][j], 0, 0, 0);
    }
    // C/D layout: col = lane&15, row = (lane>>4)*4 + reg  [m89; dtype-indep]
    const int er = fq * 4, ec = fm;
#pragma unroll
    for (int i = 0; i < 4; ++i) {
        const int gr = m0 + wr + i * 16 + er;
#pragma unroll
        for (int j = 0; j < 4; ++j) {
            const int gc = n0 + wc + j * 16 + ec;
#pragma unroll
            for (int r = 0; r < 4; ++r)
                C[(size_t)(gr + r) * ULD + gc] = (_Float16)acc[i][j][r];
        }
    }
}

// ---------------------------------------------------------------------------
// GRU GEMM (R4-verified), both gates via blockIdx.z; mcomb fused into z=0
// A-staging (agg already mean-scaled by edge kernel). LDS rows padded to 40.
// ---------------------------------------------------------------------------
__global__ __launch_bounds__(256) void gru_k(
    const _Float16* __restrict__ bigC, const float* __restrict__ agg,
    const float* __restrict__ cb, const _Float16* __restrict__ Ax,
    const _Float16* __restrict__ Bih, const _Float16* __restrict__ Bhh,
    const float* __restrict__ bih, const float* __restrict__ bhh,
    float* __restrict__ g1, float* __restrict__ g2)
{
    const int z = blockIdx.z;
    const _Float16* B = z ? Bhh : Bih;
    const float* bias = z ? bhh : bih;
    float* C = z ? g2 : g1;

    __shared__ __align__(16) _Float16 As[128 * 40];
    __shared__ __align__(16) _Float16 Bs[128 * 40];
    const int tid = threadIdx.x;
    const int lane = tid & 63, wave = tid >> 6;
    const int m0 = blockIdx.y * 128, n0 = blockIdx.x * 128;
    const int wr = (wave >> 1) * 64, wc = (wave & 1) * 64;
    const int fm = lane & 15, fq = lane >> 4;

    floatx4 acc[4][4] = {};
    for (int k0 = 0; k0 < 128; k0 += 32) {
        __syncthreads();
#pragma unroll
        for (int c = tid; c < 512; c += 256) {
            const int row = c >> 2, seg = (c & 3) << 3;
            if (z == 0) {
                const int mr = m0 + row;
                const half8 bv = *(const half8*)&bigC[(size_t)mr * ULD + 4224 + k0 + seg];
                const float4 a0 = *(const float4*)&agg[(size_t)mr * 128 + k0 + seg];
                const float4 a1 = *(const float4*)&agg[(size_t)mr * 128 + k0 + seg + 4];
                const float4 c0 = *(const float4*)&cb[k0 + seg];
                const float4 c1 = *(const float4*)&cb[k0 + seg + 4];
                _Float16 v8[8];
                v8[0] = (_Float16)fmaxf((float)bv[0] + a0.x + c0.x, 0.f);
                v8[1] = (_Float16)fmaxf((float)bv[1] + a0.y + c0.y, 0.f);
                v8[2] = (_Float16)fmaxf((float)bv[2] + a0.z + c0.z, 0.f);
                v8[3] = (_Float16)fmaxf((float)bv[3] + a0.w + c0.w, 0.f);
                v8[4] = (_Float16)fmaxf((float)bv[4] + a1.x + c1.x, 0.f);
                v8[5] = (_Float16)fmaxf((float)bv[5] + a1.y + c1.y, 0.f);
                v8[6] = (_Float16)fmaxf((float)bv[6] + a1.z + c1.z, 0.f);
                v8[7] = (_Float16)fmaxf((float)bv[7] + a1.w + c1.w, 0.f);
                *(half8*)&As[row * 40 + seg] = *(half8*)v8;
            } else {
                *(half8*)&As[row * 40 + seg] =
                    *(const half8*)&Ax[(size_t)(m0 + row) * 128 + k0 + seg];
            }
            *(half8*)&Bs[row * 40 + seg] =
                *(const half8*)&B[(size_t)(n0 + row) * 128 + k0 + seg];
        }
        __syncthreads();
        half8 af[4], bf[4];
#pragma unroll
        for (int i = 0; i < 4; ++i)
            af[i] = *(const half8*)&As[(wr + i * 16 + fm) * 40 + fq * 8];
#pragma unroll
        for (int j = 0; j < 4; ++j)
            bf[j] = *(const half8*)&Bs[(wc + j * 16 + fm) * 40 + fq * 8];
#pragma unroll
        for (int i = 0; i < 4; ++i)
#pragma unroll
            for (int j = 0; j < 4; ++j)
                acc[i][j] = __builtin_amdgcn_mfma_f32_16x16x32_f16(
                    af[i], bf[j], acc[i][j], 0, 0, 0);
    }
    const int er = fq * 4, ec = fm;
#pragma unroll
    for (int i = 0; i < 4; ++i) {
        const int gr = m0 + wr + i * 16 + er;
#pragma unroll
        for (int j = 0; j < 4; ++j) {
            const int gc = n0 + wc + j * 16 + ec;
            const float bv = bias[gc];
#pragma unroll
            for (int r = 0; r < 4; ++r)
                C[(size_t)(gr + r) * 384 + gc] = acc[i][j][r] + bv;
        }
    }
}

// ---------------------------------------------------------------------------
// Multi-role setup (one dispatch): weight casts, histograms, ehP, lin0.
// grid = 6992 blocks x 256.
// ---------------------------------------------------------------------------
__global__ __launch_bounds__(256) void setup_k(
    const float* __restrict__ x, const int* __restrict__ ei,
    const float* __restrict__ eattr, const int* __restrict__ batch,
    const float* __restrict__ lin0_w, const float* __restrict__ lin0_b,
    const float* __restrict__ nn_w1, const float* __restrict__ nn_b1,
    const float* __restrict__ w2, const float* __restrict__ b2,
    const float* __restrict__ rw, const float* __restrict__ wih,
    const float* __restrict__ whh,
    _Float16* __restrict__ BTu, _Float16* __restrict__ Bih,
    _Float16* __restrict__ Bhh, float* __restrict__ deg,
    float* __restrict__ cnt, float* __restrict__ ehP,
    float* __restrict__ xh, _Float16* __restrict__ Ax)
{
    __shared__ float As[16 * 64];
    __shared__ float Bs[16 * 64];
    const int b = blockIdx.x, t = threadIdx.x;

    if (b < 6528) {                       // BTu[t3][j][h] fp16
        const int i = b * 256 + t;        // 3*4352*128
        const int t3 = i / 557056, rem = i - t3 * 557056;
        const int j = rem >> 7, h = rem & 127;
        float v;
        if (j < 4096)      v = w2[(size_t)t3 * 524288 + (size_t)(j >> 7) * 16384 + h * 128 + (j & 127)];
        else if (j < 4224) v = b2[t3 * 16384 + h * 128 + (j - 4096)];
        else               v = rw[t3 * 16384 + h * 128 + (j - 4224)];
        BTu[i] = (_Float16)v;
    } else if (b < 6720) {                // GRU weight fp32->fp16
        const int i = (b - 6528) * 256 + t;   // 49152
        Bih[i] = (_Float16)wih[i];
        Bhh[i] = (_Float16)whh[i];
    } else if (b < 6752) {                // in-degree histogram
        const int e = (b - 6720) * 256 + t;   // 8192
        atomicAdd(&deg[ei[EE + e]], 1.0f);
    } else if (b < 6768) {                // graph-count histogram
        const int n = (b - 6752) * 256 + t;   // 4096
        atomicAdd(&cnt[batch[n]], 1.0f);
    } else if (b < 6864) {                // ehP[t3][e][33] (no inv folded)
        const int u = (b - 6768) * 256 + t;   // 24576
        const int t3 = u >> 13, e = u & 8191;
        const float ea = eattr[e];
        float* dst = ehP + (size_t)u * 33;
        for (int k = 0; k < 32; ++k) {
            float v = ea * nn_w1[t3 * 32 + k] + nn_b1[t3 * 32 + k];
            dst[k] = v > 0.f ? v : 0.f;
        }
        dst[32] = 1.0f;
    } else {                              // lin0: 128 64x64 tiles
        const int slot = b - 6864;
        const int j0 = (slot & 1) * 64, m0 = (slot >> 1) * 64;
        const int tx = t & 15, ty = t >> 4;
        const int arow = t >> 2, acol = (t & 3) << 2;
        const int bk = t >> 4, bj = (t & 15) << 2;
        float c[4][4] = {};
        for (int k0 = 0; k0 < 64; k0 += 16) {
            __syncthreads();
            float4 av = *(const float4*)&x[(size_t)(m0 + arow) * 64 + k0 + acol];
            As[(acol + 0) * 64 + arow] = av.x;
            As[(acol + 1) * 64 + arow] = av.y;
            As[(acol + 2) * 64 + arow] = av.z;
            As[(acol + 3) * 64 + arow] = av.w;
            *(float4*)&Bs[bk * 64 + bj] =
                *(const float4*)&lin0_w[(size_t)(k0 + bk) * 128 + j0 + bj];
            __syncthreads();
#pragma unroll
            for (int kk = 0; kk < 16; ++kk) {
                const float4 a = *(const float4*)&As[kk * 64 + (ty << 2)];
                const float4 bb = *(const float4*)&Bs[kk * 64 + (tx << 2)];
                c[0][0] += a.x * bb.x; c[0][1] += a.x * bb.y; c[0][2] += a.x * bb.z; c[0][3] += a.x * bb.w;
                c[1][0] += a.y * bb.x; c[1][1] += a.y * bb.y; c[1][2] += a.y * bb.z; c[1][3] += a.y * bb.w;
                c[2][0] += a.z * bb.x; c[2][1] += a.z * bb.y; c[2][2] += a.z * bb.z; c[2][3] += a.z * bb.w;
                c[3][0] += a.w * bb.x; c[3][1] += a.w * bb.y; c[3][2] += a.w * bb.z; c[3][3] += a.w * bb.w;
            }
        }
        const float4 bv = *(const float4*)&lin0_b[j0 + (tx << 2)];
        const int col0 = j0 + (tx << 2);
#pragma unroll
        for (int i = 0; i < 4; ++i) {
            const int row = m0 + (ty << 2) + i;
            float4 o;
            o.x = fmaxf(c[i][0] + bv.x, 0.f); o.y = fmaxf(c[i][1] + bv.y, 0.f);
            o.z = fmaxf(c[i][2] + bv.z, 0.f); o.w = fmaxf(c[i][3] + bv.w, 0.f);
            *(float4*)&xh[(size_t)row * 128 + col0] = o;
            _Float16* base = Ax + (size_t)row * 128 + col0;
            base[0] = (_Float16)o.x; base[1] = (_Float16)o.y;
            base[2] = (_Float16)o.z; base[3] = (_Float16)o.w;
        }
    }
}

// ---------------------------------------------------------------------------
// Edge gather + scatter (R4 body, unsorted, inv-deg applied here).
// 2 edges per 256-thread block.
// ---------------------------------------------------------------------------
__global__ __launch_bounds__(256) void edge_msg_k(
    const int* __restrict__ ei, const float* __restrict__ ehP,
    const float* __restrict__ deg, const _Float16* __restrict__ U,
    float* __restrict__ agg)
{
    __shared__ float eh[2][33];
    const int tid = threadIdx.x;
    const int half = tid >> 7;
    const int o = tid & 127;
    const int e = blockIdx.x * 2 + half;
    if (o < 33) eh[half][o] = ehP[(size_t)e * 33 + o];
    __syncthreads();
    const int r = ei[e];
    const int c = ei[EE + e];
    const float d = deg[c];
    const float inv = d > 0.f ? 1.0f / d : 0.0f;
    const _Float16* Ur = U + (size_t)r * ULD;
    float acc = eh[half][32] * (float)Ur[4096 + o];
#pragma unroll
    for (int k = 0; k < 32; ++k) acc += eh[half][k] * (float)Ur[k * 128 + o];
    atomicAdd(&agg[(size_t)c * 128 + o], acc * inv);
}

// GRU gate combine (R4 body); updates xh fp32 + Ax fp16; pool on last step
__global__ void gate_k(const float* __restrict__ G1, const float* __restrict__ G2,
                       float* __restrict__ xh, _Float16* __restrict__ Ax,
                       const int* __restrict__ batch, float* __restrict__ pooled) {
    const int idx = blockIdx.x * 256 + threadIdx.x;
    const int n = idx >> 7, o = idx & 127;
    const size_t b = (size_t)n * 384;
    float ir = G1[b + o], iz = G1[b + 128 + o], in_ = G1[b + 256 + o];
    float hr = G2[b + o], hz = G2[b + 128 + o], hn = G2[b + 256 + o];
    float r = 1.f / (1.f + expf(-(ir + hr)));
    float z = 1.f / (1.f + expf(-(iz + hz)));
    float nv = tanhf(in_ + r * hn);
    float hv = (1.f - z) * nv + z * xh[idx];
    xh[idx] = hv;
    Ax[idx] = (_Float16)hv;
    if (pooled) atomicAdd(&pooled[batch[n] * 128 + o], hv);
}

__global__ __launch_bounds__(128) void final_k(
    const float* __restrict__ pooled, const float* __restrict__ cnt,
    const float* __restrict__ l1w, const float* __restrict__ l1b,
    const float* __restrict__ l2w, const float* __restrict__ l2b,
    float* __restrict__ out)
{
    __shared__ float gv[128];
    __shared__ float sy[64];
    const int t = threadIdx.x;
    for (int g = 0; g < GG; ++g) {
        float c = cnt[g]; c = c > 1.f ? c : 1.f;
        gv[t] = pooled[g * 128 + t] / c;
        __syncthreads();
        if (t < 64) {
            float y = l1b[t];
            for (int h = 0; h < 128; ++h) y += gv[h] * l1w[h * 64 + t];
            y = y > 0.f ? y : 0.f;
            sy[t] = y * l2w[t];
        }
        __syncthreads();
        if (t == 0) {
            float s = l2b[0];
            for (int j = 0; j < 64; ++j) s += sy[j];
            out[g] = s;
        }
        __syncthreads();
    }
}

extern "C" void kernel_launch(void* const* d_in, const int* in_sizes, int n_in,
                              void* d_out, int out_size, void* d_ws, size_t ws_size,
                              hipStream_t stream) {
    const float* x      = (const float*)d_in[0];
    const int*   ei     = (const int*)d_in[1];
    const float* eattr  = (const float*)d_in[2];
    const int*   batch  = (const int*)d_in[3];
    const float* lin0_w = (const float*)d_in[4];
    const float* lin0_b = (const float*)d_in[5];
    const float* nn_w1  = (const float*)d_in[6];
    const float* nn_b1  = (const float*)d_in[7];
    const float* nn_w2  = (const float*)d_in[8];
    const float* nn_b2  = (const float*)d_in[9];
    const float* root_w = (const float*)d_in[10];
    const float* conv_b = (const float*)d_in[11];
    const float* gwih   = (const float*)d_in[12];
    const float* gwhh   = (const float*)d_in[13];
    const float* gbih   = (const float*)d_in[14];
    const float* gbhh   = (const float*)d_in[15];
    const float* l1w    = (const float*)d_in[16];
    const float* l1b    = (const float*)d_in[17];
    const float* l2w    = (const float*)d_in[18];
    const float* l2b    = (const float*)d_in[19];
    float* out = (float*)d_out;
    float* ws  = (float*)d_ws;

    // ---- workspace layout (float offsets; zero region first, contiguous) ----
    float*    agg0   = ws;                          // 3 x [4096,128]
    float*    pooled = ws + 1572864;                // [8,128]
    float*    cnt    = ws + 1573888;                // [8]
    float*    deg    = ws + 1573896;                // [4096]
    // zero region ends at 1577992 floats = 6311968 bytes
    float*    xh     = ws + 1577992;                // [4096,128] fp32
    float*    g1     = ws + 2102280;                // [4096,384] fp32
    float*    g2     = ws + 3675144;                // [4096,384] fp32
    float*    ehP    = ws + 5248008;                // [3,8192,33] fp32
    _Float16* bigC   = (_Float16*)(ws + 6059016);   // [4096,4352] fp16
    _Float16* Ax     = (_Float16*)(ws + 14971912);  // [4096,128] fp16
    _Float16* BTu    = (_Float16*)(ws + 15234056);  // 3 x [4352,128] fp16
    _Float16* Bih16  = (_Float16*)(ws + 16069640);  // [384,128] fp16
    _Float16* Bhh16  = (_Float16*)(ws + 16094216);  // [384,128] fp16

    hipMemsetAsync(agg0, 0, 6311968, stream);
    setup_k<<<6992, 256, 0, stream>>>(x, ei, eattr, batch, lin0_w, lin0_b,
                                      nn_w1, nn_b1, nn_w2, nn_b2, root_w,
                                      gwih, gwhh, BTu, Bih16, Bhh16, deg, cnt,
                                      ehP, xh, Ax);

    for (int t = 0; t < 3; ++t) {
        float* agg = agg0 + (size_t)t * 524288;
        mgemm16_k<<<dim3(34, 32), 256, 0, stream>>>(Ax, BTu + (size_t)t * 557056, bigC);
        edge_msg_k<<<EE / 2, 256, 0, stream>>>(ei, ehP + (size_t)t * EE * 33, deg, bigC, agg);
        gru_k<<<dim3(3, 32, 2), 256, 0, stream>>>(bigC, agg, conv_b + t * 128, Ax,
                                                  Bih16, Bhh16, gbih, gbhh, g1, g2);
        gate_k<<<2048, 256, 0, stream>>>(g1, g2, xh, Ax, batch,
                                         (t == 2) ? pooled : nullptr);
    }

    final_k<<<1, 128, 0, stream>>>(pooled, cnt, l1w, l1b, l2w, l2b, out);
}

// Round 9
// 319.045 us; speedup vs baseline: 3.9767x; 1.0186x over previous
//
#include <hip/hip_runtime.h>
#include <math.h>

#define NN 4096
#define EE 8192
#define HH 128
#define GG 8
#define ULD 4352          // big GEMM cols: 4096 (W2) + 128 (b2) + 128 (root)

typedef __attribute__((ext_vector_type(8))) _Float16 half8;
typedef __attribute__((ext_vector_type(4))) float floatx4;

__device__ __forceinline__ void ldst16(const _Float16* g, void* l) {
    __builtin_amdgcn_global_load_lds(
        (const __attribute__((address_space(1))) unsigned int*)g,
        (__attribute__((address_space(3))) unsigned int*)l, 16, 0, 0);
}

// ---------------------------------------------------------------------------
// fp16 MFMA GEMM (R4-verified): C[M,ULD] = A[M,128] @ BT[N,128]^T, C fp16.
// 128x128 tile/block, 4 waves (2x2 of 64x64), BK=32, K=128.
// ---------------------------------------------------------------------------
__global__ __launch_bounds__(256) void mgemm16_k(
    const _Float16* __restrict__ A, const _Float16* __restrict__ B,
    _Float16* __restrict__ C)
{
    __shared__ __align__(16) _Float16 As[128 * 32];  // [row][k]
    __shared__ __align__(16) _Float16 Bs[128 * 32];  // [col][k]
    const int tid = threadIdx.x;
    const int lane = tid & 63, wave = tid >> 6;
    const int m0 = blockIdx.y * 128, n0 = blockIdx.x * 128;
    const int wr = (wave >> 1) * 64, wc = (wave & 1) * 64;
    const int fm = lane & 15, fq = lane >> 4;

    const int srow = tid >> 2, soff = (tid & 3) << 3;
    const _Float16* gA0 = A + (size_t)(m0 + srow) * 128 + soff;
    const _Float16* gA1 = gA0 + (size_t)64 * 128;
    const _Float16* gB0 = B + (size_t)(n0 + srow) * 128 + soff;
    const _Float16* gB1 = gB0 + (size_t)64 * 128;
    char* lA0 = (char*)As + tid * 16;  char* lA1 = (char*)As + (tid + 256) * 16;
    char* lB0 = (char*)Bs + tid * 16;  char* lB1 = (char*)Bs + (tid + 256) * 16;

    floatx4 acc[4][4] = {};
    for (int k0 = 0; k0 < 128; k0 += 32) {
        __syncthreads();
        ldst16(gA0 + k0, lA0); ldst16(gA1 + k0, lA1);
        ldst16(gB0 + k0, lB0); ldst16(gB1 + k0, lB1);
        __syncthreads();
        half8 af[4], bf[4];
#pragma unroll
        for (int i = 0; i < 4; ++i)
            af[i] = *(const half8*)&As[(wr + i * 16 + fm) * 32 + fq * 8];
#pragma unroll
        for (int j = 0; j < 4; ++j)
            bf[j] = *(const half8*)&Bs[(wc + j * 16 + fm) * 32 + fq * 8];
#pragma unroll
        for (int i = 0; i < 4; ++i)
#pragma unroll
            for (int j = 0; j < 4; ++j)
                acc[i][j] = __builtin_amdgcn_mfma_f32_16x16x32_f16(
                    af[i], bf[j], acc[i][j], 0, 0, 0);
    }
    // C/D layout: col = lane&15, row = (lane>>4)*4 + reg  [m89; dtype-indep]
    const int er = fq * 4, ec = fm;
#pragma unroll
    for (int i = 0; i < 4; ++i) {
        const int gr = m0 + wr + i * 16 + er;
#pragma unroll
        for (int j = 0; j < 4; ++j) {
            const int gc = n0 + wc + j * 16 + ec;
#pragma unroll
            for (int r = 0; r < 4; ++r)
                C[(size_t)(gr + r) * ULD + gc] = (_Float16)acc[i][j][r];
        }
    }
}

// ---------------------------------------------------------------------------
// GRU GEMM (R4-verified), both gates via blockIdx.z; mcomb fused into z=0
// A-staging (agg pre-scaled by inv-deg in ehP). LDS rows padded to 40 halves.
// ---------------------------------------------------------------------------
__global__ __launch_bounds__(256) void gru_k(
    const _Float16* __restrict__ bigC, const float* __restrict__ agg,
    const float* __restrict__ cb, const _Float16* __restrict__ Ax,
    const _Float16* __restrict__ Bih, const _Float16* __restrict__ Bhh,
    const float* __restrict__ bih, const float* __restrict__ bhh,
    float* __restrict__ g1, float* __restrict__ g2)
{
    const int z = blockIdx.z;
    const _Float16* B = z ? Bhh : Bih;
    const float* bias = z ? bhh : bih;
    float* C = z ? g2 : g1;

    __shared__ __align__(16) _Float16 As[128 * 40];
    __shared__ __align__(16) _Float16 Bs[128 * 40];
    const int tid = threadIdx.x;
    const int lane = tid & 63, wave = tid >> 6;
    const int m0 = blockIdx.y * 128, n0 = blockIdx.x * 128;
    const int wr = (wave >> 1) * 64, wc = (wave & 1) * 64;
    const int fm = lane & 15, fq = lane >> 4;

    floatx4 acc[4][4] = {};
    for (int k0 = 0; k0 < 128; k0 += 32) {
        __syncthreads();
#pragma unroll
        for (int c = tid; c < 512; c += 256) {
            const int row = c >> 2, seg = (c & 3) << 3;
            if (z == 0) {
                const int mr = m0 + row;
                const half8 bv = *(const half8*)&bigC[(size_t)mr * ULD + 4224 + k0 + seg];
                const float4 a0 = *(const float4*)&agg[(size_t)mr * 128 + k0 + seg];
                const float4 a1 = *(const float4*)&agg[(size_t)mr * 128 + k0 + seg + 4];
                const float4 c0 = *(const float4*)&cb[k0 + seg];
                const float4 c1 = *(const float4*)&cb[k0 + seg + 4];
                _Float16 v8[8];
                v8[0] = (_Float16)fmaxf((float)bv[0] + a0.x + c0.x, 0.f);
                v8[1] = (_Float16)fmaxf((float)bv[1] + a0.y + c0.y, 0.f);
                v8[2] = (_Float16)fmaxf((float)bv[2] + a0.z + c0.z, 0.f);
                v8[3] = (_Float16)fmaxf((float)bv[3] + a0.w + c0.w, 0.f);
                v8[4] = (_Float16)fmaxf((float)bv[4] + a1.x + c1.x, 0.f);
                v8[5] = (_Float16)fmaxf((float)bv[5] + a1.y + c1.y, 0.f);
                v8[6] = (_Float16)fmaxf((float)bv[6] + a1.z + c1.z, 0.f);
                v8[7] = (_Float16)fmaxf((float)bv[7] + a1.w + c1.w, 0.f);
                *(half8*)&As[row * 40 + seg] = *(half8*)v8;
            } else {
                *(half8*)&As[row * 40 + seg] =
                    *(const half8*)&Ax[(size_t)(m0 + row) * 128 + k0 + seg];
            }
            *(half8*)&Bs[row * 40 + seg] =
                *(const half8*)&B[(size_t)(n0 + row) * 128 + k0 + seg];
        }
        __syncthreads();
        half8 af[4], bf[4];
#pragma unroll
        for (int i = 0; i < 4; ++i)
            af[i] = *(const half8*)&As[(wr + i * 16 + fm) * 40 + fq * 8];
#pragma unroll
        for (int j = 0; j < 4; ++j)
            bf[j] = *(const half8*)&Bs[(wc + j * 16 + fm) * 40 + fq * 8];
#pragma unroll
        for (int i = 0; i < 4; ++i)
#pragma unroll
            for (int j = 0; j < 4; ++j)
                acc[i][j] = __builtin_amdgcn_mfma_f32_16x16x32_f16(
                    af[i], bf[j], acc[i][j], 0, 0, 0);
    }
    const int er = fq * 4, ec = fm;
#pragma unroll
    for (int i = 0; i < 4; ++i) {
        const int gr = m0 + wr + i * 16 + er;
#pragma unroll
        for (int j = 0; j < 4; ++j) {
            const int gc = n0 + wc + j * 16 + ec;
            const float bv = bias[gc];
#pragma unroll
            for (int r = 0; r < 4; ++r)
                C[(size_t)(gr + r) * 384 + gc] = acc[i][j][r] + bv;
        }
    }
}

// ---------------------------------------------------------------------------
// Multi-role setup (one dispatch, 502 blocks x 256):
//  [0,102)   LDS-tiled coalesced transpose of W2/b2/root -> BTu fp16
//  [102,294) GRU weight fp32->fp16 cast
//  [294,326) in-degree histogram     [326,342) graph-count histogram
//  [342,374) out-degree histogram    [374,502) lin0 64x64 tiles
// ---------------------------------------------------------------------------
__global__ __launch_bounds__(256) void setup_k(
    const float* __restrict__ x, const int* __restrict__ ei,
    const int* __restrict__ batch,
    const float* __restrict__ lin0_w, const float* __restrict__ lin0_b,
    const float* __restrict__ w2, const float* __restrict__ b2,
    const float* __restrict__ rw, const float* __restrict__ wih,
    const float* __restrict__ whh,
    _Float16* __restrict__ BTu, _Float16* __restrict__ Bih,
    _Float16* __restrict__ Bhh, float* __restrict__ deg,
    int* __restrict__ odeg, float* __restrict__ cnt,
    float* __restrict__ xh, _Float16* __restrict__ Ax)
{
    __shared__ __align__(16) char sm[33024];
    const int b = blockIdx.x, t = threadIdx.x;

    if (b < 102) {
        // transpose one 128x128 tile: dst[j0+o][h] = src[h][o]
        const int t3 = b / 34, m = b % 34;
        const float* src = (m < 32) ? w2 + (size_t)t3 * 524288 + (size_t)m * 16384
                         : (m == 32) ? b2 + t3 * 16384 : rw + t3 * 16384;
        _Float16* dst = BTu + (size_t)t3 * 557056 + (size_t)m * 16384;
        float* tile = (float*)sm;                    // [64][129]
        for (int h0 = 0; h0 < 128; h0 += 64) {
            __syncthreads();
#pragma unroll
            for (int i = 0; i < 8; ++i) {
                const int q = i * 256 + t;           // float4 index in 64x128
                const int h = q >> 5, o4 = (q & 31) * 4;
                const float4 v = *(const float4*)&src[(size_t)(h0 + h) * 128 + o4];
                float* row = tile + h * 129 + o4;
                row[0] = v.x; row[1] = v.y; row[2] = v.z; row[3] = v.w;
            }
            __syncthreads();
            const int o = t >> 1, hh0 = (t & 1) * 32;
            __align__(16) _Float16 buf[32];
#pragma unroll
            for (int s = 0; s < 32; ++s)
                buf[s] = (_Float16)tile[(hh0 + s) * 129 + o];
            _Float16* d = dst + (size_t)o * 128 + h0 + hh0;
            *(half8*)&d[0]  = *(half8*)&buf[0];
            *(half8*)&d[8]  = *(half8*)&buf[8];
            *(half8*)&d[16] = *(half8*)&buf[16];
            *(half8*)&d[24] = *(half8*)&buf[24];
        }
    } else if (b < 294) {                 // GRU weight cast (coalesced copy)
        const int i = (b - 102) * 256 + t;    // 49152
        Bih[i] = (_Float16)wih[i];
        Bhh[i] = (_Float16)whh[i];
    } else if (b < 326) {                 // in-degree
        const int e = (b - 294) * 256 + t;    // 8192
        atomicAdd(&deg[ei[EE + e]], 1.0f);
    } else if (b < 342) {                 // graph-count
        const int n = (b - 326) * 256 + t;    // 4096
        atomicAdd(&cnt[batch[n]], 1.0f);
    } else if (b < 374) {                 // out-degree (for counting sort)
        const int e = (b - 342) * 256 + t;    // 8192
        atomicAdd(&odeg[ei[e]], 1);
    } else {                              // lin0: 128 64x64 tiles
        float* As = (float*)sm;
        float* Bs = (float*)(sm + 4096);
        const int slot = b - 374;
        const int j0 = (slot & 1) * 64, m0 = (slot >> 1) * 64;
        const int tx = t & 15, ty = t >> 4;
        const int arow = t >> 2, acol = (t & 3) << 2;
        const int bk = t >> 4, bj = (t & 15) << 2;
        float c[4][4] = {};
        for (int k0 = 0; k0 < 64; k0 += 16) {
            __syncthreads();
            float4 av = *(const float4*)&x[(size_t)(m0 + arow) * 64 + k0 + acol];
            As[(acol + 0) * 64 + arow] = av.x;
            As[(acol + 1) * 64 + arow] = av.y;
            As[(acol + 2) * 64 + arow] = av.z;
            As[(acol + 3) * 64 + arow] = av.w;
            *(float4*)&Bs[bk * 64 + bj] =
                *(const float4*)&lin0_w[(size_t)(k0 + bk) * 128 + j0 + bj];
            __syncthreads();
#pragma unroll
            for (int kk = 0; kk < 16; ++kk) {
                const float4 a = *(const float4*)&As[kk * 64 + (ty << 2)];
                const float4 bb = *(const float4*)&Bs[kk * 64 + (tx << 2)];
                c[0][0] += a.x * bb.x; c[0][1] += a.x * bb.y; c[0][2] += a.x * bb.z; c[0][3] += a.x * bb.w;
                c[1][0] += a.y * bb.x; c[1][1] += a.y * bb.y; c[1][2] += a.y * bb.z; c[1][3] += a.y * bb.w;
                c[2][0] += a.z * bb.x; c[2][1] += a.z * bb.y; c[2][2] += a.z * bb.z; c[2][3] += a.z * bb.w;
                c[3][0] += a.w * bb.x; c[3][1] += a.w * bb.y; c[3][2] += a.w * bb.z; c[3][3] += a.w * bb.w;
            }
        }
        const float4 bv = *(const float4*)&lin0_b[j0 + (tx << 2)];
        const int col0 = j0 + (tx << 2);
#pragma unroll
        for (int i = 0; i < 4; ++i) {
            const int row = m0 + (ty << 2) + i;
            float4 o;
            o.x = fmaxf(c[i][0] + bv.x, 0.f); o.y = fmaxf(c[i][1] + bv.y, 0.f);
            o.z = fmaxf(c[i][2] + bv.z, 0.f); o.w = fmaxf(c[i][3] + bv.w, 0.f);
            *(float4*)&xh[(size_t)row * 128 + col0] = o;
            _Float16* base = Ax + (size_t)row * 128 + col0;
            base[0] = (_Float16)o.x; base[1] = (_Float16)o.y;
            base[2] = (_Float16)o.z; base[3] = (_Float16)o.w;
        }
    }
}

// exclusive prefix sum of odeg[4096] -> ocur (single block)  [R4-verified]
__global__ __launch_bounds__(256) void scan_k(const int* __restrict__ odeg,
                                              int* __restrict__ ocur) {
    __shared__ int ps[256];
    const int t = threadIdx.x;
    const int base = t * 16;
    int l[16]; int s = 0;
#pragma unroll
    for (int i = 0; i < 16; ++i) { l[i] = s; s += odeg[base + i]; }
    ps[t] = s;
    __syncthreads();
    for (int d = 1; d < 256; d <<= 1) {
        int v = (t >= d) ? ps[t - d] : 0;
        __syncthreads();
        ps[t] += v;
        __syncthreads();
    }
    const int excl = (t == 0) ? 0 : ps[t - 1];
#pragma unroll
    for (int i = 0; i < 16; ++i) ocur[base + i] = excl + l[i];
}

// counting-sort scatter by source + per-edge coefficient tables  [R4-verified]
__global__ void scatter_k(const int* __restrict__ ei, const float* __restrict__ eattr,
                          const float* __restrict__ w1, const float* __restrict__ b1,
                          const float* __restrict__ deg, int* __restrict__ ocur,
                          int2* __restrict__ rc, float* __restrict__ ehP) {
    const int e = blockIdx.x * 256 + threadIdx.x;
    const int r = ei[e], c = ei[EE + e];
    const int pos = atomicAdd(&ocur[r], 1);
    rc[pos] = make_int2(r, c);
    const float d = deg[c];
    const float inv = d > 0.f ? 1.0f / d : 0.0f;
    const float ea = eattr[e];
    for (int t = 0; t < 3; ++t) {
        float* dst = ehP + ((size_t)t * EE + pos) * 33;
        for (int k = 0; k < 32; ++k) {
            float v = ea * w1[t * 32 + k] + b1[t * 32 + k];
            dst[k] = (v > 0.f ? v : 0.f) * inv;
        }
        dst[32] = inv;
    }
}

// ---------------------------------------------------------------------------
// Edge gather + scatter (R4-verified): source-sorted via rc, XCD-swizzled.
// ---------------------------------------------------------------------------
__global__ __launch_bounds__(256) void edge_msg_k(
    const int2* __restrict__ rc, const float* __restrict__ ehP,
    const _Float16* __restrict__ U, float* __restrict__ agg)
{
    __shared__ float eh[2][33];
    const int b = blockIdx.x;                      // 4096 pairs
    const int p0 = ((b & 7) * 512 + (b >> 3)) * 2; // XCD-contiguous sorted ranges
    const int half = threadIdx.x >> 7;
    const int o = threadIdx.x & 127;
    if (o < 33) eh[half][o] = ehP[(size_t)(p0 + half) * 33 + o];
    __syncthreads();
    const int2 e = rc[p0 + half];
    const _Float16* Ur = U + (size_t)e.x * ULD;
    float acc = eh[half][32] * (float)Ur[4096 + o];
#pragma unroll
    for (int k = 0; k < 32; ++k) acc += eh[half][k] * (float)Ur[k * 128 + o];
    atomicAdd(&agg[(size_t)e.y * 128 + o], acc);
}

// GRU gate combine (R4-verified); updates xh fp32 + Ax fp16; pool on last step
__global__ void gate_k(const float* __restrict__ G1, const float* __restrict__ G2,
                       float* __restrict__ xh, _Float16* __restrict__ Ax,
                       const int* __restrict__ batch, float* __restrict__ pooled) {
    const int idx = blockIdx.x * 256 + threadIdx.x;
    const int n = idx >> 7, o = idx & 127;
    const size_t b = (size_t)n * 384;
    float ir = G1[b + o], iz = G1[b + 128 + o], in_ = G1[b + 256 + o];
    float hr = G2[b + o], hz = G2[b + 128 + o], hn = G2[b + 256 + o];
    float r = 1.f / (1.f + expf(-(ir + hr)));
    float z = 1.f / (1.f + expf(-(iz + hz)));
    float nv = tanhf(in_ + r * hn);
    float hv = (1.f - z) * nv + z * xh[idx];
    xh[idx] = hv;
    Ax[idx] = (_Float16)hv;
    if (pooled) atomicAdd(&pooled[batch[n] * 128 + o], hv);
}

__global__ __launch_bounds__(128) void final_k(
    const float* __restrict__ pooled, const float* __restrict__ cnt,
    const float* __restrict__ l1w, const float* __restrict__ l1b,
    const float* __restrict__ l2w, const float* __restrict__ l2b,
    float* __restrict__ out)
{
    __shared__ float gv[128];
    __shared__ float sy[64];
    const int t = threadIdx.x;
    for (int g = 0; g < GG; ++g) {
        float c = cnt[g]; c = c > 1.f ? c : 1.f;
        gv[t] = pooled[g * 128 + t] / c;
        __syncthreads();
        if (t < 64) {
            float y = l1b[t];
            for (int h = 0; h < 128; ++h) y += gv[h] * l1w[h * 64 + t];
            y = y > 0.f ? y : 0.f;
            sy[t] = y * l2w[t];
        }
        __syncthreads();
        if (t == 0) {
            float s = l2b[0];
            for (int j = 0; j < 64; ++j) s += sy[j];
            out[g] = s;
        }
        __syncthreads();
    }
}

extern "C" void kernel_launch(void* const* d_in, const int* in_sizes, int n_in,
                              void* d_out, int out_size, void* d_ws, size_t ws_size,
                              hipStream_t stream) {
    const float* x      = (const float*)d_in[0];
    const int*   ei     = (const int*)d_in[1];
    const float* eattr  = (const float*)d_in[2];
    const int*   batch  = (const int*)d_in[3];
    const float* lin0_w = (const float*)d_in[4];
    const float* lin0_b = (const float*)d_in[5];
    const float* nn_w1  = (const float*)d_in[6];
    const float* nn_b1  = (const float*)d_in[7];
    const float* nn_w2  = (const float*)d_in[8];
    const float* nn_b2  = (const float*)d_in[9];
    const float* root_w = (const float*)d_in[10];
    const float* conv_b = (const float*)d_in[11];
    const float* gwih   = (const float*)d_in[12];
    const float* gwhh   = (const float*)d_in[13];
    const float* gbih   = (const float*)d_in[14];
    const float* gbhh   = (const float*)d_in[15];
    const float* l1w    = (const float*)d_in[16];
    const float* l1b    = (const float*)d_in[17];
    const float* l2w    = (const float*)d_in[18];
    const float* l2b    = (const float*)d_in[19];
    float* out = (float*)d_out;
    float* ws  = (float*)d_ws;

    // ---- workspace layout (R4; float offsets; zero region first) ----
    float*    agg0   = ws;                          // 3 x [4096,128]
    float*    pooled = ws + 1572864;                // [8,128]
    float*    cnt    = ws + 1573888;                // [8]
    float*    deg    = ws + 1573896;                // [4096]
    int*      odeg   = (int*)(ws + 1577992);        // [4096]
    // zero region ends at 1582088 floats = 6328352 bytes
    int*      ocur   = (int*)(ws + 1582088);        // [4096]
    int2*     rc     = (int2*)(ws + 1586184);       // [8192]
    float*    ehP    = ws + 1602568;                // [3,8192,33]
    float*    xh     = ws + 2413576;                // [4096,128]
    float*    g1     = ws + 2937864;                // [4096,384]
    float*    g2     = ws + 4510728;                // [4096,384]
    _Float16* bigC   = (_Float16*)(ws + 6083592);   // [4096,4352] fp16
    _Float16* Ax     = (_Float16*)(ws + 14996488);  // [4096,128] fp16
    _Float16* BTu    = (_Float16*)(ws + 15258632);  // 3 x [4352,128] fp16
    _Float16* Bih16  = (_Float16*)(ws + 16094216);  // [384,128] fp16
    _Float16* Bhh16  = (_Float16*)(ws + 16118792);  // [384,128] fp16

    hipMemsetAsync(agg0, 0, 6328352, stream);
    setup_k<<<502, 256, 0, stream>>>(x, ei, batch, lin0_w, lin0_b,
                                     nn_w2, nn_b2, root_w, gwih, gwhh,
                                     BTu, Bih16, Bhh16, deg, odeg, cnt, xh, Ax);
    scan_k<<<1, 256, 0, stream>>>(odeg, ocur);
    scatter_k<<<EE / 256, 256, 0, stream>>>(ei, eattr, nn_w1, nn_b1, deg, ocur, rc, ehP);

    for (int t = 0; t < 3; ++t) {
        float* agg = agg0 + (size_t)t * 524288;
        mgemm16_k<<<dim3(34, 32), 256, 0, stream>>>(Ax, BTu + (size_t)t * 557056, bigC);
        edge_msg_k<<<EE / 2, 256, 0, stream>>>(rc, ehP + (size_t)t * EE * 33, bigC, agg);
        gru_k<<<dim3(3, 32, 2), 256, 0, stream>>>(bigC, agg, conv_b + t * 128, Ax,
                                                  Bih16, Bhh16, gbih, gbhh, g1, g2);
        gate_k<<<2048, 256, 0, stream>>>(g1, g2, xh, Ax, batch,
                                         (t == 2) ? pooled : nullptr);
    }

    final_k<<<1, 128, 0, stream>>>(pooled, cnt, l1w, l1b, l2w, l2b, out);
}